// Round 1
// baseline (495.507 us; speedup 1.0000x reference)
//
#include <hip/hip_runtime.h>
#include <math.h>

#define ST 48  // LDS row stride (floats) for blur tiles: 16B-aligned, fits 44-wide + overreach

struct GaussW { float w3[3]; float w5[5]; float w7[7]; };

__global__ __launch_bounds__(256) void zero_k(float* __restrict__ out, float* __restrict__ S) {
  int i = blockIdx.x * 256 + threadIdx.x;
  if (i < 65536) out[i] = 0.f;
  if (i < 1024) S[i] = 0.f;
}

__device__ __forceinline__ float4 ldsf4(const float* p) { return *(const float4*)p; }

// One block = one 32x32 output tile of one (b,c) image.
// ctx = x - blur7(blur5(blur3(x))), with per-level crop-to-image (zero outside).
__global__ __launch_bounds__(256) void blur_k(const float* __restrict__ x,
                                              float* __restrict__ ctx,
                                              float* __restrict__ S,
                                              GaussW w) {
  __shared__ __align__(16) float xb[44 * ST];
  __shared__ __align__(16) float b1[44 * ST];
  __shared__ __align__(16) float b2[44 * ST];
  __shared__ float wsum[4];

  const int tid = threadIdx.x;
  const int bi = blockIdx.x;
  const int img = bi >> 6;          // b*64 + c, 1024 images
  const int tile = bi & 63;         // 8x8 tiles of 32x32
  const int oy = (tile >> 3) << 5;
  const int ox = (tile & 7) << 5;
  const float* xg = x + ((size_t)img << 16);

  // ---- load x halo tile: image rows [oy-6,oy+38) x cols [ox-6,ox+38) -> xb[44][44]
  for (int u = tid; u < 44 * 11; u += 256) {
    int r = u / 11, c4 = (u % 11) << 2;
    int gy = oy + r - 6;
    float v0 = 0.f, v1 = 0.f, v2 = 0.f, v3 = 0.f;
    if ((unsigned)gy < 256u) {
      int gx = ox + c4 - 6;
      const float* rp = xg + gy * 256 + gx;
      if ((unsigned)(gx + 0) < 256u) v0 = rp[0];
      if ((unsigned)(gx + 1) < 256u) v1 = rp[1];
      if ((unsigned)(gx + 2) < 256u) v2 = rp[2];
      if ((unsigned)(gx + 3) < 256u) v3 = rp[3];
    }
    *(float4*)&xb[r * ST + c4] = make_float4(v0, v1, v2, v3);
  }
  __syncthreads();

  // ---- t1 = hconv3(x): 44 rows x 42 cols -> b1  (t1[r][c] uses x cols c..c+2)
  for (int u = tid; u < 44 * 11; u += 256) {
    int r = u / 11, c4 = (u % 11) << 2;
    const float* p = &xb[r * ST + c4];
    float4 a = ldsf4(p), b = ldsf4(p + 4);
    float v0=a.x, v1=a.y, v2=a.z, v3=a.w, v4=b.x, v5=b.y;
    float4 o;
    o.x = w.w3[0]*v0 + w.w3[1]*v1 + w.w3[2]*v2;
    o.y = w.w3[0]*v1 + w.w3[1]*v2 + w.w3[2]*v3;
    o.z = w.w3[0]*v2 + w.w3[1]*v3 + w.w3[2]*v4;
    o.w = w.w3[0]*v3 + w.w3[1]*v4 + w.w3[2]*v5;
    *(float4*)&b1[r * ST + c4] = o;
  }
  __syncthreads();

  // ---- G1 = vconv3(t1), cropped: 42x42 -> b2. G1[r][c] ~ image (oy+r-5, ox+c-5)
  for (int u = tid; u < 42 * 11; u += 256) {
    int r = u / 11, c4 = (u % 11) << 2;
    const float* p = &b1[r * ST + c4];
    float4 s0 = ldsf4(p), s1 = ldsf4(p + ST), s2 = ldsf4(p + 2 * ST);
    float o0 = w.w3[0]*s0.x + w.w3[1]*s1.x + w.w3[2]*s2.x;
    float o1 = w.w3[0]*s0.y + w.w3[1]*s1.y + w.w3[2]*s2.y;
    float o2 = w.w3[0]*s0.z + w.w3[1]*s1.z + w.w3[2]*s2.z;
    float o3 = w.w3[0]*s0.w + w.w3[1]*s1.w + w.w3[2]*s2.w;
    bool rok = (unsigned)(oy + r - 5) < 256u;
    int ix = ox + c4 - 5;
    float4 o;
    o.x = (rok && (unsigned)(ix + 0) < 256u) ? o0 : 0.f;
    o.y = (rok && (unsigned)(ix + 1) < 256u) ? o1 : 0.f;
    o.z = (rok && (unsigned)(ix + 2) < 256u) ? o2 : 0.f;
    o.w = (rok && (unsigned)(ix + 3) < 256u) ? o3 : 0.f;
    *(float4*)&b2[r * ST + c4] = o;
  }
  __syncthreads();

  // ---- t2 = hconv5(G1): 42 rows x 38 cols -> b1  (t2[r][c] uses G1 cols c..c+4)
  for (int u = tid; u < 42 * 10; u += 256) {
    int r = u / 10, c4 = (u % 10) << 2;
    const float* p = &b2[r * ST + c4];
    float4 a = ldsf4(p), b = ldsf4(p + 4);
    float v[8] = {a.x, a.y, a.z, a.w, b.x, b.y, b.z, b.w};
    float o[4];
    #pragma unroll
    for (int j = 0; j < 4; ++j)
      o[j] = w.w5[0]*v[j] + w.w5[1]*v[j+1] + w.w5[2]*v[j+2] + w.w5[3]*v[j+3] + w.w5[4]*v[j+4];
    *(float4*)&b1[r * ST + c4] = make_float4(o[0], o[1], o[2], o[3]);
  }
  __syncthreads();

  // ---- G2 = vconv5(t2), cropped: 38x38 -> b2. G2[r][c] ~ image (oy+r-3, ox+c-3)
  for (int u = tid; u < 38 * 10; u += 256) {
    int r = u / 10, c4 = (u % 10) << 2;
    const float* p = &b1[r * ST + c4];
    float o0 = 0.f, o1 = 0.f, o2 = 0.f, o3 = 0.f;
    #pragma unroll
    for (int j = 0; j < 5; ++j) {
      float4 s = ldsf4(p + j * ST);
      o0 += w.w5[j] * s.x; o1 += w.w5[j] * s.y; o2 += w.w5[j] * s.z; o3 += w.w5[j] * s.w;
    }
    bool rok = (unsigned)(oy + r - 3) < 256u;
    int ix = ox + c4 - 3;
    float4 o;
    o.x = (rok && (unsigned)(ix + 0) < 256u) ? o0 : 0.f;
    o.y = (rok && (unsigned)(ix + 1) < 256u) ? o1 : 0.f;
    o.z = (rok && (unsigned)(ix + 2) < 256u) ? o2 : 0.f;
    o.w = (rok && (unsigned)(ix + 3) < 256u) ? o3 : 0.f;
    *(float4*)&b2[r * ST + c4] = o;
  }
  __syncthreads();

  // ---- t3 = hconv7(G2): 38 rows x 32 cols -> b1  (t3[r][c] uses G2 cols c..c+6)
  for (int u = tid; u < 38 * 8; u += 256) {
    int r = u >> 3, c4 = (u & 7) << 2;
    const float* p = &b2[r * ST + c4];
    float4 a = ldsf4(p), b = ldsf4(p + 4), c = ldsf4(p + 8);
    float v[10] = {a.x, a.y, a.z, a.w, b.x, b.y, b.z, b.w, c.x, c.y};
    float o[4];
    #pragma unroll
    for (int j = 0; j < 4; ++j) {
      float acc = 0.f;
      #pragma unroll
      for (int tp = 0; tp < 7; ++tp) acc += w.w7[tp] * v[j + tp];
      o[j] = acc;
    }
    *(float4*)&b1[r * ST + c4] = make_float4(o[0], o[1], o[2], o[3]);
  }
  __syncthreads();

  // ---- G3 = vconv7(t3): 32x32; ctx = x - G3; partial sum of exp(ctx)
  float le = 0.f;
  {
    int u = tid;                     // exactly 256 units: 32 rows x 8 col4-units
    int r = u >> 3, c4 = (u & 7) << 2;
    const float* p = &b1[r * ST + c4];
    float o0 = 0.f, o1 = 0.f, o2 = 0.f, o3 = 0.f;
    #pragma unroll
    for (int j = 0; j < 7; ++j) {
      float4 s = ldsf4(p + j * ST);
      o0 += w.w7[j] * s.x; o1 += w.w7[j] * s.y; o2 += w.w7[j] * s.z; o3 += w.w7[j] * s.w;
    }
    const float* q = &xb[(r + 6) * ST + c4 + 4];   // x center cols c4+6..c4+9
    float4 m0 = ldsf4(q), m1 = ldsf4(q + 4);
    float c0 = m0.z - o0, c1 = m0.w - o1, c2 = m1.x - o2, c3 = m1.y - o3;
    size_t base = ((size_t)img << 16) + (size_t)(oy + r) * 256 + (ox + c4);
    *(float4*)&ctx[base] = make_float4(c0, c1, c2, c3);
    le = __expf(c0) + __expf(c1) + __expf(c2) + __expf(c3);
  }
  #pragma unroll
  for (int off = 32; off >= 1; off >>= 1) le += __shfl_down(le, off);
  if ((tid & 63) == 0) wsum[tid >> 6] = le;
  __syncthreads();
  if (tid == 0) atomicAdd(&S[img], wsum[0] + wsum[1] + wsum[2] + wsum[3]);
}

// att accumulation: block = (chunk ci of 1024 n's, batch b).
// acc[d][e] += exp(ctx[b,d,n]) * ctx[b,e,n] over the chunk; atomicAdd into out.
__global__ __launch_bounds__(256) void att_k(const float* __restrict__ ctx,
                                             float* __restrict__ attacc) {
  __shared__ __align__(16) float ct[64 * 68];  // [n_local][d], stride 68 keeps 16B align
  __shared__ __align__(16) float et[64 * 68];
  const int t = threadIdx.x;
  const int ci = blockIdx.x;   // 64 chunks
  const int b = blockIdx.y;    // 16 batches
  const int d0 = (t >> 4) << 2;
  const int e0 = (t & 15) << 2;
  const float* cb = ctx + ((size_t)b << 22);
  float acc[4][4] = {};
  for (int sub = 0; sub < 16; ++sub) {
    const int n0 = (ci << 10) + (sub << 6);
    #pragma unroll
    for (int i = 0; i < 16; ++i) {
      int e = i * 256 + t;
      int d = e >> 6, nl = e & 63;
      float v = cb[((size_t)d << 16) + n0 + nl];
      ct[nl * 68 + d] = v;
      et[nl * 68 + d] = __expf(v);
    }
    __syncthreads();
    #pragma unroll 16
    for (int nl = 0; nl < 64; ++nl) {
      float4 ed = *(const float4*)&et[nl * 68 + d0];
      float4 cv = *(const float4*)&ct[nl * 68 + e0];
      acc[0][0] += ed.x * cv.x; acc[0][1] += ed.x * cv.y; acc[0][2] += ed.x * cv.z; acc[0][3] += ed.x * cv.w;
      acc[1][0] += ed.y * cv.x; acc[1][1] += ed.y * cv.y; acc[1][2] += ed.y * cv.z; acc[1][3] += ed.y * cv.w;
      acc[2][0] += ed.z * cv.x; acc[2][1] += ed.z * cv.y; acc[2][2] += ed.z * cv.z; acc[2][3] += ed.z * cv.w;
      acc[3][0] += ed.w * cv.x; acc[3][1] += ed.w * cv.y; acc[3][2] += ed.w * cv.z; acc[3][3] += ed.w * cv.w;
    }
    __syncthreads();
  }
  float* ap = attacc + ((size_t)(b * 64 + d0) << 6) + e0;
  #pragma unroll
  for (int i = 0; i < 4; ++i) {
    #pragma unroll
    for (int j = 0; j < 4; ++j) atomicAdd(ap + ((size_t)i << 6) + j, acc[i][j]);
  }
}

__global__ __launch_bounds__(256) void fin_k(float* __restrict__ out, const float* __restrict__ S) {
  int i = blockIdx.x * 256 + threadIdx.x;  // 65536 = 16*64*64
  out[i] = out[i] / S[i >> 6];
}

extern "C" void kernel_launch(void* const* d_in, const int* in_sizes, int n_in,
                              void* d_out, int out_size, void* d_ws, size_t ws_size,
                              hipStream_t stream) {
  const float* x = (const float*)d_in[0];
  float* out = (float*)d_out;
  float* ctx = (float*)d_ws;                                   // 16*64*256*256 fp32 = 256 MiB
  float* S = (float*)((char*)d_ws + (size_t)67108864 * 4);     // 1024 fp32
  if (ws_size < (size_t)67108864 * 4 + 4096) return;           // need 256MiB+4KB scratch

  GaussW w;
  double s = pow(2.0, 1.0 / 3.0);
  double sig[3] = {1.6, 1.6 * s, 1.6 * s * s};
  float* wp[3] = {w.w3, w.w5, w.w7};
  for (int lv = 0; lv < 3; ++lv) {
    int k = 2 * lv + 3;
    double tmp[7], sum = 0.0;
    for (int i = 0; i < k; ++i) {
      double a = i - (k - 1) / 2.0;
      tmp[i] = exp(-a * a / (2.0 * sig[lv] * sig[lv]));
      sum += tmp[i];
    }
    for (int i = 0; i < k; ++i) wp[lv][i] = (float)(tmp[i] / sum);
  }

  zero_k<<<dim3(256), dim3(256), 0, stream>>>(out, S);
  blur_k<<<dim3(65536), dim3(256), 0, stream>>>(x, ctx, S, w);
  att_k<<<dim3(64, 16), dim3(256), 0, stream>>>(ctx, out);
  fin_k<<<dim3(256), dim3(256), 0, stream>>>(out, S);
}